// Round 6
// baseline (433.660 us; speedup 1.0000x reference)
//
#include <hip/hip_runtime.h>

#define N_NODES 200000
#define N_EDGES 6400000
#define K_BUCKETS 64
#define BUCKET 3125         // 64*3125 = 200000 exactly; dl < 4096 (12 bits)
#define NSB 3200            // chunks (stage 1)
#define CHUNK 2000          // NSB*CHUNK == N_EDGES exactly
#define CPB 64              // stage-2 chunks per bucket (64*2000=128k >= max bucket len)

__device__ __forceinline__ unsigned short f2bf(float x) {
    unsigned u = __float_as_uint(x);
    u += 0x7fffu + ((u >> 16) & 1u);      // RNE to bf16
    return (unsigned short)(u >> 16);
}
__device__ __forceinline__ float bf2f(unsigned short h) {
    return __uint_as_float((unsigned)h << 16);
}

// ---------------- fast path ----------------

// x_out = z0 ; u0 = a0.z0 ; v0 = q0.z0   (S0 = 0)
__global__ __launch_bounds__(256) void prep_kernel(
    const float4* __restrict__ z, float4* __restrict__ x_out,
    const float* __restrict__ W,
    float* __restrict__ u, float* __restrict__ v)
{
    int n = blockIdx.x * 256 + threadIdx.x;
    if (n >= N_NODES) return;
    float4 zv = z[n];
    x_out[n] = zv;
    float a0 = W[0], a1 = W[1], a2 = W[2], a3 = W[3];
    float q0 = W[4], q1 = W[5], q2 = W[6], q3 = W[7];
    u[n] = a0 * zv.x + a1 * zv.y + a2 * zv.z + a3 * zv.w;
    v[n] = q0 * zv.x + q1 * zv.y + q2 * zv.z + q3 * zv.w;
}

// per-chunk bucket histogram (dst), layout counts[sb*K + k]
__global__ __launch_bounds__(256) void hist_kernel(const int* __restrict__ dst,
                                                   int* __restrict__ counts)
{
    __shared__ int cnt[K_BUCKETS];
    int tid = threadIdx.x, sb = blockIdx.x;
    if (tid < K_BUCKETS) cnt[tid] = 0;
    __syncthreads();
    int e0 = sb * CHUNK;
    for (int i = tid; i < CHUNK; i += 256)
        atomicAdd(&cnt[dst[e0 + i] / BUCKET], 1);
    __syncthreads();
    if (tid < K_BUCKETS) counts[sb * K_BUCKETS + tid] = cnt[tid];
}

// per-bucket exclusive scan across chunks
__global__ __launch_bounds__(256) void scan_cols(const int* __restrict__ counts,
                                                 int* __restrict__ baseRel,
                                                 int* __restrict__ tot)
{
    __shared__ int buf[256];
    __shared__ int carry_s;
    int k = blockIdx.x, tid = threadIdx.x;
    if (tid == 0) carry_s = 0;
    __syncthreads();
    for (int base = 0; base < NSB; base += 256) {
        int idx = base + tid;
        int v = (idx < NSB) ? counts[idx * K_BUCKETS + k] : 0;
        buf[tid] = v;
        __syncthreads();
        for (int off = 1; off < 256; off <<= 1) {
            int t = (tid >= off) ? buf[tid - off] : 0;
            __syncthreads();
            buf[tid] += t;
            __syncthreads();
        }
        int incl = buf[tid];
        if (idx < NSB) baseRel[idx * K_BUCKETS + k] = carry_s + incl - v;
        __syncthreads();
        if (tid == 255) carry_s += incl;
        __syncthreads();
    }
    if (tid == 255) tot[k] = carry_s;
}

// scan 64 bucket totals -> bstart[0..64]
__global__ __launch_bounds__(64) void scan_tot(const int* __restrict__ tot,
                                               int* __restrict__ bstart)
{
    __shared__ int buf[K_BUCKETS];
    int tid = threadIdx.x;
    int v = tot[tid];
    buf[tid] = v;
    __syncthreads();
    for (int off = 1; off < K_BUCKETS; off <<= 1) {
        int t = (tid >= off) ? buf[tid - off] : 0;
        __syncthreads();
        buf[tid] += t;
        __syncthreads();
    }
    bstart[tid] = buf[tid] - v;
    if (tid == K_BUCKETS - 1) bstart[K_BUCKETS] = buf[tid];
}

// stage-1 counting-sort scatter by dst-bucket (unchanged from R5; runs ~31)
__global__ __launch_bounds__(256) void scatter_kernel(
    const int* __restrict__ src, const int* __restrict__ dst,
    const float* __restrict__ r, const float* __restrict__ r_hat,
    const float* __restrict__ W, const float* __restrict__ b,
    const int* __restrict__ counts, const int* __restrict__ baseRel,
    const int* __restrict__ bstart,
    int* __restrict__ packedA, unsigned short* __restrict__ c0a,
    unsigned short* __restrict__ c1a, unsigned short* __restrict__ c2a)
{
    __shared__ int cur[K_BUCKETS];
    __shared__ int delta[K_BUCKETS];
    __shared__ int scanbuf[K_BUCKETS];
    __shared__ int            lpack[CHUNK];
    __shared__ unsigned short lc0[CHUNK];
    __shared__ unsigned short lc1[CHUNK];
    __shared__ unsigned short lc2[CHUNK];
    __shared__ unsigned char  skb[CHUNK];

    int tid = threadIdx.x, sb = blockIdx.x;

    if (tid < K_BUCKETS) scanbuf[tid] = counts[sb * K_BUCKETS + tid];
    __syncthreads();
    for (int off = 1; off < K_BUCKETS; off <<= 1) {
        int t = 0;
        if (tid < K_BUCKETS && tid >= off) t = scanbuf[tid - off];
        __syncthreads();
        if (tid < K_BUCKETS) scanbuf[tid] += t;
        __syncthreads();
    }
    if (tid < K_BUCKETS) {
        int v = counts[sb * K_BUCKETS + tid];
        int localBase = scanbuf[tid] - v;
        int gBase = bstart[tid] + baseRel[sb * K_BUCKETS + tid];
        delta[tid] = gBase - localBase;
        cur[tid] = localBase;
    }
    __syncthreads();

    float w8_0 = W[8],  w9_0 = W[9],  w10_0 = W[10], w11_0 = W[11], b0 = b[0];
    float w8_1 = W[20], w9_1 = W[21], w10_1 = W[22], w11_1 = W[23], b1 = b[1];
    float w8_2 = W[32], w9_2 = W[33], w10_2 = W[34], w11_2 = W[35], b2 = b[2];

    int e0 = sb * CHUNK;
    for (int i = tid; i < CHUNK; i += 256) {
        int e = e0 + i;
        int d = dst[e];
        int k = d / BUCKET;
        int dl = d - k * BUCKET;
        int slot = atomicAdd(&cur[k], 1);
        int sn = src[e];
        float rv = r[e];
        size_t he = 3 * (size_t)e;
        float h0 = r_hat[he], h1 = r_hat[he + 1], h2 = r_hat[he + 2];
        lpack[slot] = (sn << 12) | dl;
        lc0[slot] = f2bf(w8_0 * rv + w9_0 * h0 + w10_0 * h1 + w11_0 * h2 + b0);
        lc1[slot] = f2bf(w8_1 * rv + w9_1 * h0 + w10_1 * h1 + w11_1 * h2 + b1);
        lc2[slot] = f2bf(w8_2 * rv + w9_2 * h0 + w10_2 * h1 + w11_2 * h2 + b2);
        skb[slot] = (unsigned char)k;
    }
    __syncthreads();

    for (int s = tid; s < CHUNK; s += 256) {
        int k = skb[s];
        int gpos = delta[k] + s;
        packedA[gpos] = lpack[s];
        c0a[gpos] = lc0[s];
        c1a[gpos] = lc1[s];
        c2a[gpos] = lc2[s];
    }
}

// ---------------- stage 2 (Tier A): within-bucket stable sort by src-region ----
// Co-locates the ~8 edges per (src cache line, dst bucket) so pagg's u[s]
// gather becomes an L1-resident sliding window (L2 line traffic / ~8).

// per (bucket, chunk) histogram of srcb = src/BUCKET
__global__ __launch_bounds__(256) void hist2_kernel(
    const int* __restrict__ packedA, const int* __restrict__ bstart,
    int* __restrict__ counts2)
{
    __shared__ int cnt[K_BUCKETS];
    int tid = threadIdx.x, blk = blockIdx.x;
    int k = blk >> 6, ci = blk & 63;
    if (tid < K_BUCKETS) cnt[tid] = 0;
    __syncthreads();
    int lo = bstart[k] + ci * CHUNK;
    int hi = min(lo + CHUNK, bstart[k + 1]);
    for (int j = lo + tid; j < hi; j += 256)
        atomicAdd(&cnt[(packedA[j] >> 12) / BUCKET], 1);
    __syncthreads();
    if (tid < K_BUCKETS) counts2[blk * K_BUCKETS + tid] = cnt[tid];
}

// per bucket: bucket-relative base for each (chunk, srcb)
__global__ __launch_bounds__(256) void scan2_kernel(
    const int* __restrict__ counts2, int* __restrict__ baseRel2)
{
    __shared__ int m[CPB * K_BUCKETS];   // 16 KB
    __shared__ int colT[K_BUCKETS];
    __shared__ int colB[K_BUCKETS];
    int k = blockIdx.x, tid = threadIdx.x;
    for (int i = tid; i < CPB * K_BUCKETS; i += 256)
        m[i] = counts2[k * CPB * K_BUCKETS + i];
    __syncthreads();
    if (tid < K_BUCKETS) {           // exclusive scan over chunks per srcb
        int s = tid, t = 0;
        for (int ci = 0; ci < CPB; ++ci) {
            int v = m[ci * K_BUCKETS + s];
            m[ci * K_BUCKETS + s] = t;
            t += v;
        }
        colT[s] = t;
    }
    __syncthreads();
    if (tid == 0) {                  // exclusive scan over srcb
        int t = 0;
        for (int s = 0; s < K_BUCKETS; ++s) { colB[s] = t; t += colT[s]; }
    }
    __syncthreads();
    for (int i = tid; i < CPB * K_BUCKETS; i += 256) {
        int s = i & 63;
        baseRel2[k * CPB * K_BUCKETS + i] = colB[s] + m[i];
    }
}

// permute (packedA, c*) -> (packedB, c*b), srcb-major within each bucket
__global__ __launch_bounds__(256) void scatter2_kernel(
    const int* __restrict__ packedA,
    const unsigned short* __restrict__ c0a, const unsigned short* __restrict__ c1a,
    const unsigned short* __restrict__ c2a,
    const int* __restrict__ bstart, const int* __restrict__ counts2,
    const int* __restrict__ baseRel2,
    int* __restrict__ packedB,
    unsigned short* __restrict__ c0b, unsigned short* __restrict__ c1b,
    unsigned short* __restrict__ c2b)
{
    __shared__ int cur[K_BUCKETS];
    __shared__ int delta[K_BUCKETS];
    __shared__ int scanbuf[K_BUCKETS];
    __shared__ int            lpack[CHUNK];
    __shared__ unsigned short lc0[CHUNK];
    __shared__ unsigned short lc1[CHUNK];
    __shared__ unsigned short lc2[CHUNK];
    __shared__ unsigned char  skb[CHUNK];

    int tid = threadIdx.x, blk = blockIdx.x;
    int k = blk >> 6, ci = blk & 63;
    int lo = bstart[k] + ci * CHUNK;
    int hi = min(lo + CHUNK, bstart[k + 1]);
    int n = hi - lo;
    if (n <= 0) return;              // uniform across block

    if (tid < K_BUCKETS) scanbuf[tid] = counts2[blk * K_BUCKETS + tid];
    __syncthreads();
    for (int off = 1; off < K_BUCKETS; off <<= 1) {
        int t = 0;
        if (tid < K_BUCKETS && tid >= off) t = scanbuf[tid - off];
        __syncthreads();
        if (tid < K_BUCKETS) scanbuf[tid] += t;
        __syncthreads();
    }
    if (tid < K_BUCKETS) {
        int v = counts2[blk * K_BUCKETS + tid];
        int localBase = scanbuf[tid] - v;
        int gBase = bstart[k] + baseRel2[blk * K_BUCKETS + tid];
        delta[tid] = gBase - localBase;
        cur[tid] = localBase;
    }
    __syncthreads();

    for (int j = lo + tid; j < hi; j += 256) {
        int pack = packedA[j];
        int s = (pack >> 12) / BUCKET;
        int slot = atomicAdd(&cur[s], 1);
        lpack[slot] = pack;
        lc0[slot] = c0a[j];
        lc1[slot] = c1a[j];
        lc2[slot] = c2a[j];
        skb[slot] = (unsigned char)s;
    }
    __syncthreads();

    for (int t = tid; t < n; t += 256) {
        int s = skb[t];
        int g = delta[s] + t;
        packedB[g] = lpack[t];
        c0b[g] = lc0[t];
        c1b[g] = lc1[t];
        c2b[g] = lc2[t];
    }
}

// partial aggregation (shared by tiers); ps = blocks per bucket.
// Tier A (src-sorted input): u[s] window is L1-resident -> L2 traffic /8.
__global__ __launch_bounds__(1024) void pagg_kernel(
    const int* __restrict__ packed, const unsigned short* __restrict__ ca,
    const int* __restrict__ bstart,
    const float* __restrict__ u, const float* __restrict__ v,
    float* __restrict__ partial, int ps)
{
    __shared__ float vsl[BUCKET];
    __shared__ float aggsl[BUCKET];
    int tid = threadIdx.x, blk = blockIdx.x;
    int k = blk / ps;
    int p = blk - k * ps;
    int nbase = k * BUCKET;

    for (int i = tid; i < BUCKET; i += 1024) {
        aggsl[i] = 0.0f;
        vsl[i] = v[nbase + i];
    }
    __syncthreads();

    int estart = bstart[k], eend = bstart[k + 1];
    int len = eend - estart;
    int per = (len + ps - 1) / ps;
    int lo = estart + p * per;
    int hi = min(lo + per, eend);

    for (int j = lo + tid; j < hi; j += 1024) {
        int pack = packed[j];
        int s = pack >> 12;
        int dl = pack & 4095;
        unsafeAtomicAdd(&aggsl[dl], u[s] + vsl[dl] + bf2f(ca[j]));   // ds_add_f32
    }
    __syncthreads();

    float* pout = partial + (size_t)blk * BUCKET;
    for (int i = tid; i < BUCKET; i += 1024) pout[i] = aggsl[i];
}

// finalize layer: S' = S + sum(partials); compute next u,v (or final z)
__global__ __launch_bounds__(256) void fin_kernel(
    const float4* __restrict__ z0, const float* __restrict__ partial,
    const float* __restrict__ Sin, float* __restrict__ Sout,
    const float* __restrict__ W, int layer, int ps,
    float* __restrict__ u, float* __restrict__ v, float4* __restrict__ z_out)
{
    int n = blockIdx.x * 256 + threadIdx.x;
    if (n >= N_NODES) return;
    int k = n / BUCKET;
    int i = n - k * BUCKET;
    float agg = 0.0f;
    const float* pk = partial + (size_t)k * ps * BUCKET + i;
    for (int p = 0; p < ps; ++p) agg += pk[(size_t)p * BUCKET];
    float S = ((layer == 0) ? 0.0f : Sin[n]) + agg;
    if (layer < 2) {
        const float* Wn = W + 12 * (layer + 1);
        float a0 = Wn[0], a1 = Wn[1], a2 = Wn[2], a3 = Wn[3];
        float q0 = Wn[4], q1 = Wn[5], q2 = Wn[6], q3 = Wn[7];
        float A = a0 + a1 + a2 + a3, B = q0 + q1 + q2 + q3;
        float4 zv = z0[n];
        Sout[n] = S;
        u[n] = a0 * zv.x + a1 * zv.y + a2 * zv.z + a3 * zv.w + A * S;
        v[n] = q0 * zv.x + q1 * zv.y + q2 * zv.z + q3 * zv.w + B * S;
    } else {
        float4 zv = z0[n];
        zv.x += S; zv.y += S; zv.z += S; zv.w += S;
        z_out[n] = zv;
    }
}

// ---------------- fallback (round-2) ----------------

__global__ __launch_bounds__(256) void init_kernel(
    const float4* __restrict__ z_in, float4* __restrict__ z_cur,
    float4* __restrict__ x_out, float* __restrict__ agg)
{
    int n = blockIdx.x * blockDim.x + threadIdx.x;
    if (n < N_NODES) {
        float4 vv = z_in[n];
        z_cur[n] = vv; x_out[n] = vv; agg[n] = 0.0f;
    }
}

__global__ __launch_bounds__(256) void edge_kernel(
    const float* __restrict__ z, const float* __restrict__ r,
    const float* __restrict__ r_hat, const int* __restrict__ src,
    const int* __restrict__ dst, const float* __restrict__ Wl,
    const float* __restrict__ bl, float* __restrict__ agg)
{
    int e = blockIdx.x * blockDim.x + threadIdx.x;
    if (e >= N_EDGES) return;
    float w0 = Wl[0], w1 = Wl[1], w2 = Wl[2], w3 = Wl[3];
    float w4 = Wl[4], w5 = Wl[5], w6 = Wl[6], w7 = Wl[7];
    float w8 = Wl[8], w9 = Wl[9], w10 = Wl[10], w11 = Wl[11];
    float bias = bl[0];
    int s = src[e], d = dst[e];
    float4 zs = ((const float4*)z)[s];
    float4 zd = ((const float4*)z)[d];
    float rv = r[e];
    const float* rh = r_hat + 3 * (size_t)e;
    float msg = w0*zs.x + w1*zs.y + w2*zs.z + w3*zs.w
              + w4*zd.x + w5*zd.y + w6*zd.z + w7*zd.w
              + w8*rv + w9*rh[0] + w10*rh[1] + w11*rh[2] + bias;
    unsafeAtomicAdd(&agg[d], msg);
}

__global__ __launch_bounds__(256) void node_update(float4* __restrict__ z_cur,
                                                   float* __restrict__ agg)
{
    int n = blockIdx.x * blockDim.x + threadIdx.x;
    if (n < N_NODES) {
        float a = agg[n]; float4 vv = z_cur[n];
        vv.x += a; vv.y += a; vv.z += a; vv.w += a;
        z_cur[n] = vv; agg[n] = 0.0f;
    }
}

__global__ __launch_bounds__(256) void final_update(const float4* __restrict__ z_cur,
                                                    const float* __restrict__ agg,
                                                    float4* __restrict__ z_out)
{
    int n = blockIdx.x * blockDim.x + threadIdx.x;
    if (n < N_NODES) {
        float a = agg[n]; float4 vv = z_cur[n];
        vv.x += a; vv.y += a; vv.z += a; vv.w += a;
        z_out[n] = vv;
    }
}

// ---------------- launch ----------------

extern "C" void kernel_launch(void* const* d_in, const int* in_sizes, int n_in,
                              void* d_out, int out_size, void* d_ws, size_t ws_size,
                              hipStream_t stream)
{
    const float* z     = (const float*)d_in[0];
    const float* r     = (const float*)d_in[1];
    const float* r_hat = (const float*)d_in[2];
    const float* W     = (const float*)d_in[3];
    const float* b     = (const float*)d_in[4];
    const int*   src   = (const int*)d_in[5];
    const int*   dst   = (const int*)d_in[6];
    float* out = (float*)d_out;

    char* ws = (char*)d_ws;
    size_t off = 0;
    auto alloc = [&](size_t bytes) {
        void* p = ws + off;
        off += (bytes + 15) & ~(size_t)15;
        return p;
    };
    // ---- Tier B footprint (R5 pipeline) ----
    int*            packedA = (int*)alloc((size_t)N_EDGES * 4);
    unsigned short* c0a     = (unsigned short*)alloc((size_t)N_EDGES * 2);
    unsigned short* c1a     = (unsigned short*)alloc((size_t)N_EDGES * 2);
    unsigned short* c2a     = (unsigned short*)alloc((size_t)N_EDGES * 2);
    int*            counts  = (int*)alloc((size_t)NSB * K_BUCKETS * 4);
    int*            baseRel = (int*)alloc((size_t)NSB * K_BUCKETS * 4);
    int*            tot     = (int*)alloc((size_t)K_BUCKETS * 4);
    int*            bstart  = (int*)alloc((size_t)(K_BUCKETS + 1) * 4);
    float*          Sa      = (float*)alloc((size_t)N_NODES * 4);
    float*          Sb      = (float*)alloc((size_t)N_NODES * 4);
    float*          ubuf    = (float*)alloc((size_t)N_NODES * 4);
    float*          vbuf    = (float*)alloc((size_t)N_NODES * 4);
    float*          partial = (float*)alloc((size_t)K_BUCKETS * 8 * BUCKET * 4);
    size_t requiredB = off;
    // ---- Tier A extras (stage-2 src-locality sort) ----
    int*            counts2  = (int*)alloc((size_t)K_BUCKETS * CPB * K_BUCKETS * 4);
    int*            baseRel2 = (int*)alloc((size_t)K_BUCKETS * CPB * K_BUCKETS * 4);
    int*            packedB  = (int*)alloc((size_t)N_EDGES * 4);
    unsigned short* c0b      = (unsigned short*)alloc((size_t)N_EDGES * 2);
    unsigned short* c1b      = (unsigned short*)alloc((size_t)N_EDGES * 2);
    unsigned short* c2b      = (unsigned short*)alloc((size_t)N_EDGES * 2);
    size_t requiredA = off;

    dim3 nblk((N_NODES + 255) / 256);

    if (ws_size >= requiredB) {
        bool tierA = (ws_size >= requiredA);
        prep_kernel<<<nblk, 256, 0, stream>>>(
            (const float4*)z, (float4*)(out + 4 * (size_t)N_NODES), W, ubuf, vbuf);
        hist_kernel<<<NSB, 256, 0, stream>>>(dst, counts);
        scan_cols<<<K_BUCKETS, 256, 0, stream>>>(counts, baseRel, tot);
        scan_tot<<<1, 64, 0, stream>>>(tot, bstart);
        scatter_kernel<<<NSB, 256, 0, stream>>>(src, dst, r, r_hat, W, b,
                                                counts, baseRel, bstart,
                                                packedA, c0a, c1a, c2a);
        const int* pk = packedA;
        const unsigned short *x0 = c0a, *x1 = c1a, *x2 = c2a;
        int ps = 8;
        if (tierA) {
            hist2_kernel<<<K_BUCKETS * CPB, 256, 0, stream>>>(packedA, bstart, counts2);
            scan2_kernel<<<K_BUCKETS, 256, 0, stream>>>(counts2, baseRel2);
            scatter2_kernel<<<K_BUCKETS * CPB, 256, 0, stream>>>(
                packedA, c0a, c1a, c2a, bstart, counts2, baseRel2,
                packedB, c0b, c1b, c2b);
            pk = packedB; x0 = c0b; x1 = c1b; x2 = c2b;
            ps = 4;   // 256 blocks, ~1/CU: private L1 for the sliding src window
        }
        // layer 0
        pagg_kernel<<<K_BUCKETS * ps, 1024, 0, stream>>>(pk, x0, bstart, ubuf, vbuf, partial, ps);
        fin_kernel<<<nblk, 256, 0, stream>>>(
            (const float4*)z, partial, Sa, Sa, W, 0, ps, ubuf, vbuf, (float4*)out);
        // layer 1
        pagg_kernel<<<K_BUCKETS * ps, 1024, 0, stream>>>(pk, x1, bstart, ubuf, vbuf, partial, ps);
        fin_kernel<<<nblk, 256, 0, stream>>>(
            (const float4*)z, partial, Sa, Sb, W, 1, ps, ubuf, vbuf, (float4*)out);
        // layer 2
        pagg_kernel<<<K_BUCKETS * ps, 1024, 0, stream>>>(pk, x2, bstart, ubuf, vbuf, partial, ps);
        fin_kernel<<<nblk, 256, 0, stream>>>(
            (const float4*)z, partial, Sb, Sb, W, 2, ps, ubuf, vbuf, (float4*)out);
    } else {
        // fallback: round-2 path
        float* agg   = (float*)d_ws;
        float* z_cur = agg + N_NODES;
        dim3 eblk((N_EDGES + 255) / 256);
        init_kernel<<<nblk, 256, 0, stream>>>(
            (const float4*)z, (float4*)z_cur,
            (float4*)(out + 4 * (size_t)N_NODES), agg);
        for (int i = 0; i < 3; ++i) {
            edge_kernel<<<eblk, 256, 0, stream>>>(
                z_cur, r, r_hat, src, dst, W + 12 * i, b + i, agg);
            if (i < 2)
                node_update<<<nblk, 256, 0, stream>>>((float4*)z_cur, agg);
            else
                final_update<<<nblk, 256, 0, stream>>>(
                    (const float4*)z_cur, agg, (float4*)out);
        }
    }
}

// Round 7
// 368.252 us; speedup vs baseline: 1.1776x; 1.1776x over previous
//
#include <hip/hip_runtime.h>

#define N_NODES 200000
#define N_EDGES 6400000
#define K_BUCKETS 64
#define BUCKET 3125         // 64*3125 = 200000 exactly; dl < 4096 (12 bits)
#define NSB 3125            // chunks
#define CHUNK 2048          // NSB*CHUNK == N_EDGES exactly; /4 = 512 quads
#define P_SPLIT 8           // blocks per bucket in aggregation (512 blocks, 1024 thr)

__device__ __forceinline__ unsigned short f2bf(float x) {
    unsigned u = __float_as_uint(x);
    u += 0x7fffu + ((u >> 16) & 1u);      // RNE to bf16
    return (unsigned short)(u >> 16);
}
__device__ __forceinline__ float bf2f(unsigned short h) {
    return __uint_as_float((unsigned)h << 16);
}

// ---------------- fast path ----------------

// x_out = z0 ; u0 = a0.z0 ; v0 = q0.z0   (S0 = 0)
__global__ __launch_bounds__(256) void prep_kernel(
    const float4* __restrict__ z, float4* __restrict__ x_out,
    const float* __restrict__ W,
    float* __restrict__ u, float* __restrict__ v)
{
    int n = blockIdx.x * 256 + threadIdx.x;
    if (n >= N_NODES) return;
    float4 zv = z[n];
    x_out[n] = zv;
    float a0 = W[0], a1 = W[1], a2 = W[2], a3 = W[3];
    float q0 = W[4], q1 = W[5], q2 = W[6], q3 = W[7];
    u[n] = a0 * zv.x + a1 * zv.y + a2 * zv.z + a3 * zv.w;
    v[n] = q0 * zv.x + q1 * zv.y + q2 * zv.z + q3 * zv.w;
}

// per-chunk bucket histogram (dst), int4-vectorized loads
__global__ __launch_bounds__(256) void hist_kernel(const int* __restrict__ dst,
                                                   int* __restrict__ counts)
{
    __shared__ int cnt[K_BUCKETS];
    int tid = threadIdx.x, sb = blockIdx.x;
    if (tid < K_BUCKETS) cnt[tid] = 0;
    __syncthreads();
    const int4* d4 = reinterpret_cast<const int4*>(dst + sb * CHUNK);
    for (int i4 = tid; i4 < CHUNK / 4; i4 += 256) {
        int4 dd = d4[i4];
        atomicAdd(&cnt[dd.x / BUCKET], 1);
        atomicAdd(&cnt[dd.y / BUCKET], 1);
        atomicAdd(&cnt[dd.z / BUCKET], 1);
        atomicAdd(&cnt[dd.w / BUCKET], 1);
    }
    __syncthreads();
    if (tid < K_BUCKETS) counts[sb * K_BUCKETS + tid] = cnt[tid];
}

// per-bucket exclusive scan across chunks
__global__ __launch_bounds__(256) void scan_cols(const int* __restrict__ counts,
                                                 int* __restrict__ baseRel,
                                                 int* __restrict__ tot)
{
    __shared__ int buf[256];
    __shared__ int carry_s;
    int k = blockIdx.x, tid = threadIdx.x;
    if (tid == 0) carry_s = 0;
    __syncthreads();
    for (int base = 0; base < NSB; base += 256) {
        int idx = base + tid;
        int v = (idx < NSB) ? counts[idx * K_BUCKETS + k] : 0;
        buf[tid] = v;
        __syncthreads();
        for (int off = 1; off < 256; off <<= 1) {
            int t = (tid >= off) ? buf[tid - off] : 0;
            __syncthreads();
            buf[tid] += t;
            __syncthreads();
        }
        int incl = buf[tid];
        if (idx < NSB) baseRel[idx * K_BUCKETS + k] = carry_s + incl - v;
        __syncthreads();
        if (tid == 255) carry_s += incl;
        __syncthreads();
    }
    if (tid == 255) tot[k] = carry_s;
}

// scan 64 bucket totals -> bstart[0..64]
__global__ __launch_bounds__(64) void scan_tot(const int* __restrict__ tot,
                                               int* __restrict__ bstart)
{
    __shared__ int buf[K_BUCKETS];
    int tid = threadIdx.x;
    int v = tot[tid];
    buf[tid] = v;
    __syncthreads();
    for (int off = 1; off < K_BUCKETS; off <<= 1) {
        int t = (tid >= off) ? buf[tid - off] : 0;
        __syncthreads();
        buf[tid] += t;
        __syncthreads();
    }
    bstart[tid] = buf[tid] - v;
    if (tid == K_BUCKETS - 1) bstart[K_BUCKETS] = buf[tid];
}

// counting-sort scatter, int4/float4-vectorized global reads (4 edges/epoch)
__global__ __launch_bounds__(256) void scatter_kernel(
    const int* __restrict__ src, const int* __restrict__ dst,
    const float* __restrict__ r, const float* __restrict__ r_hat,
    const float* __restrict__ W, const float* __restrict__ b,
    const int* __restrict__ counts, const int* __restrict__ baseRel,
    const int* __restrict__ bstart,
    int* __restrict__ packedA, unsigned short* __restrict__ c0a,
    unsigned short* __restrict__ c1a, unsigned short* __restrict__ c2a)
{
    __shared__ int cur[K_BUCKETS];
    __shared__ int delta[K_BUCKETS];
    __shared__ int scanbuf[K_BUCKETS];
    __shared__ int            lpack[CHUNK];
    __shared__ unsigned short lc0[CHUNK];
    __shared__ unsigned short lc1[CHUNK];
    __shared__ unsigned short lc2[CHUNK];
    __shared__ unsigned char  skb[CHUNK];

    int tid = threadIdx.x, sb = blockIdx.x;

    if (tid < K_BUCKETS) scanbuf[tid] = counts[sb * K_BUCKETS + tid];
    __syncthreads();
    for (int off = 1; off < K_BUCKETS; off <<= 1) {
        int t = 0;
        if (tid < K_BUCKETS && tid >= off) t = scanbuf[tid - off];
        __syncthreads();
        if (tid < K_BUCKETS) scanbuf[tid] += t;
        __syncthreads();
    }
    if (tid < K_BUCKETS) {
        int v = counts[sb * K_BUCKETS + tid];
        int localBase = scanbuf[tid] - v;
        int gBase = bstart[tid] + baseRel[sb * K_BUCKETS + tid];
        delta[tid] = gBase - localBase;
        cur[tid] = localBase;
    }
    __syncthreads();

    float w8_0 = W[8],  w9_0 = W[9],  w10_0 = W[10], w11_0 = W[11], b0 = b[0];
    float w8_1 = W[20], w9_1 = W[21], w10_1 = W[22], w11_1 = W[23], b1 = b[1];
    float w8_2 = W[32], w9_2 = W[33], w10_2 = W[34], w11_2 = W[35], b2 = b[2];

    int e0 = sb * CHUNK;
    const int4*   s4  = reinterpret_cast<const int4*>(src + e0);
    const int4*   d4  = reinterpret_cast<const int4*>(dst + e0);
    const float4* rr4 = reinterpret_cast<const float4*>(r + e0);
    const float4* rh4 = reinterpret_cast<const float4*>(r_hat + 3 * (size_t)e0);

    // pass B: 4 edges per load-epoch
    for (int i4 = tid; i4 < CHUNK / 4; i4 += 256) {
        int4 ss = s4[i4];
        int4 dd = d4[i4];
        float4 rv = rr4[i4];
        float4 ha = rh4[3 * i4];
        float4 hb = rh4[3 * i4 + 1];
        float4 hc = rh4[3 * i4 + 2];

        #define PROC(SN, DN, RV, H0, H1, H2)                                   \
        {                                                                      \
            int k = (DN) / BUCKET;                                             \
            int dl = (DN) - k * BUCKET;                                        \
            int slot = atomicAdd(&cur[k], 1);                                  \
            lpack[slot] = ((SN) << 12) | dl;                                   \
            lc0[slot] = f2bf(w8_0 * (RV) + w9_0 * (H0) + w10_0 * (H1) + w11_0 * (H2) + b0); \
            lc1[slot] = f2bf(w8_1 * (RV) + w9_1 * (H0) + w10_1 * (H1) + w11_1 * (H2) + b1); \
            lc2[slot] = f2bf(w8_2 * (RV) + w9_2 * (H0) + w10_2 * (H1) + w11_2 * (H2) + b2); \
            skb[slot] = (unsigned char)k;                                      \
        }
        PROC(ss.x, dd.x, rv.x, ha.x, ha.y, ha.z)
        PROC(ss.y, dd.y, rv.y, ha.w, hb.x, hb.y)
        PROC(ss.z, dd.z, rv.z, hb.z, hb.w, hc.x)
        PROC(ss.w, dd.w, rv.w, hc.y, hc.z, hc.w)
        #undef PROC
    }
    __syncthreads();

    // pass C: sequential LDS reads, run-coalesced global stores
    for (int s = tid; s < CHUNK; s += 256) {
        int k = skb[s];
        int gpos = delta[k] + s;
        packedA[gpos] = lpack[s];
        c0a[gpos] = lc0[s];
        c1a[gpos] = lc1[s];
        c2a[gpos] = lc2[s];
    }
}

// partial aggregation, int4/ushort4-vectorized: 4 edges per load-epoch.
// Scalar head/tail handle bucket-boundary misalignment (bstart arbitrary mod 4).
__global__ __launch_bounds__(1024) void pagg_kernel(
    const int* __restrict__ packed, const unsigned short* __restrict__ ca,
    const int* __restrict__ bstart,
    const float* __restrict__ u, const float* __restrict__ v,
    float* __restrict__ partial)
{
    __shared__ float vsl[BUCKET];
    __shared__ float aggsl[BUCKET];
    int tid = threadIdx.x, blk = blockIdx.x;
    int k = blk >> 3;                 // P_SPLIT == 8
    int p = blk & 7;
    int nbase = k * BUCKET;

    for (int i = tid; i < BUCKET; i += 1024) {
        aggsl[i] = 0.0f;
        vsl[i] = v[nbase + i];
    }
    __syncthreads();

    int A = bstart[k], B = bstart[k + 1];
    int A4 = min(B, (A + 3) & ~3);
    int nq = (B - A4) >> 2;           // full quads
    int B4 = A4 + (nq << 2);

    if (p == 0 && tid < (A4 - A)) {   // scalar head (<=3)
        int j = A + tid;
        int pk = packed[j];
        int dl = pk & 4095;
        unsafeAtomicAdd(&aggsl[dl], u[pk >> 12] + vsl[dl] + bf2f(ca[j]));
    }
    if (p == P_SPLIT - 1 && tid < (B - B4)) {   // scalar tail (<=3)
        int j = B4 + tid;
        int pk = packed[j];
        int dl = pk & 4095;
        unsafeAtomicAdd(&aggsl[dl], u[pk >> 12] + vsl[dl] + bf2f(ca[j]));
    }

    int qper = (nq + P_SPLIT - 1) / P_SPLIT;
    int qlo = p * qper;
    int qhi = min(nq, qlo + qper);
    for (int q = qlo + tid; q < qhi; q += 1024) {
        int j = A4 + (q << 2);
        int4 pk4 = *reinterpret_cast<const int4*>(packed + j);
        ushort4 c4 = *reinterpret_cast<const ushort4*>(ca + j);
        float u0 = u[pk4.x >> 12];
        float u1 = u[pk4.y >> 12];
        float u2 = u[pk4.z >> 12];
        float u3 = u[pk4.w >> 12];
        int d0 = pk4.x & 4095, d1 = pk4.y & 4095;
        int d2 = pk4.z & 4095, d3 = pk4.w & 4095;
        unsafeAtomicAdd(&aggsl[d0], u0 + vsl[d0] + bf2f(c4.x));
        unsafeAtomicAdd(&aggsl[d1], u1 + vsl[d1] + bf2f(c4.y));
        unsafeAtomicAdd(&aggsl[d2], u2 + vsl[d2] + bf2f(c4.z));
        unsafeAtomicAdd(&aggsl[d3], u3 + vsl[d3] + bf2f(c4.w));
    }
    __syncthreads();

    float* pout = partial + (size_t)blk * BUCKET;
    for (int i = tid; i < BUCKET; i += 1024) pout[i] = aggsl[i];
}

// finalize layer: S' = S + sum(partials); compute next u,v (or final z)
__global__ __launch_bounds__(256) void fin_kernel(
    const float4* __restrict__ z0, const float* __restrict__ partial,
    const float* __restrict__ Sin, float* __restrict__ Sout,
    const float* __restrict__ W, int layer,
    float* __restrict__ u, float* __restrict__ v, float4* __restrict__ z_out)
{
    int n = blockIdx.x * 256 + threadIdx.x;
    if (n >= N_NODES) return;
    int k = n / BUCKET;
    int i = n - k * BUCKET;
    float agg = 0.0f;
    const float* pk = partial + (size_t)k * P_SPLIT * BUCKET + i;
#pragma unroll
    for (int p = 0; p < P_SPLIT; ++p) agg += pk[(size_t)p * BUCKET];
    float S = ((layer == 0) ? 0.0f : Sin[n]) + agg;
    if (layer < 2) {
        const float* Wn = W + 12 * (layer + 1);
        float a0 = Wn[0], a1 = Wn[1], a2 = Wn[2], a3 = Wn[3];
        float q0 = Wn[4], q1 = Wn[5], q2 = Wn[6], q3 = Wn[7];
        float A = a0 + a1 + a2 + a3, B = q0 + q1 + q2 + q3;
        float4 zv = z0[n];
        Sout[n] = S;
        u[n] = a0 * zv.x + a1 * zv.y + a2 * zv.z + a3 * zv.w + A * S;
        v[n] = q0 * zv.x + q1 * zv.y + q2 * zv.z + q3 * zv.w + B * S;
    } else {
        float4 zv = z0[n];
        zv.x += S; zv.y += S; zv.z += S; zv.w += S;
        z_out[n] = zv;
    }
}

// ---------------- fallback (round-2) ----------------

__global__ __launch_bounds__(256) void init_kernel(
    const float4* __restrict__ z_in, float4* __restrict__ z_cur,
    float4* __restrict__ x_out, float* __restrict__ agg)
{
    int n = blockIdx.x * blockDim.x + threadIdx.x;
    if (n < N_NODES) {
        float4 vv = z_in[n];
        z_cur[n] = vv; x_out[n] = vv; agg[n] = 0.0f;
    }
}

__global__ __launch_bounds__(256) void edge_kernel(
    const float* __restrict__ z, const float* __restrict__ r,
    const float* __restrict__ r_hat, const int* __restrict__ src,
    const int* __restrict__ dst, const float* __restrict__ Wl,
    const float* __restrict__ bl, float* __restrict__ agg)
{
    int e = blockIdx.x * blockDim.x + threadIdx.x;
    if (e >= N_EDGES) return;
    float w0 = Wl[0], w1 = Wl[1], w2 = Wl[2], w3 = Wl[3];
    float w4 = Wl[4], w5 = Wl[5], w6 = Wl[6], w7 = Wl[7];
    float w8 = Wl[8], w9 = Wl[9], w10 = Wl[10], w11 = Wl[11];
    float bias = bl[0];
    int s = src[e], d = dst[e];
    float4 zs = ((const float4*)z)[s];
    float4 zd = ((const float4*)z)[d];
    float rv = r[e];
    const float* rh = r_hat + 3 * (size_t)e;
    float msg = w0*zs.x + w1*zs.y + w2*zs.z + w3*zs.w
              + w4*zd.x + w5*zd.y + w6*zd.z + w7*zd.w
              + w8*rv + w9*rh[0] + w10*rh[1] + w11*rh[2] + bias;
    unsafeAtomicAdd(&agg[d], msg);
}

__global__ __launch_bounds__(256) void node_update(float4* __restrict__ z_cur,
                                                   float* __restrict__ agg)
{
    int n = blockIdx.x * blockDim.x + threadIdx.x;
    if (n < N_NODES) {
        float a = agg[n]; float4 vv = z_cur[n];
        vv.x += a; vv.y += a; vv.z += a; vv.w += a;
        z_cur[n] = vv; agg[n] = 0.0f;
    }
}

__global__ __launch_bounds__(256) void final_update(const float4* __restrict__ z_cur,
                                                    const float* __restrict__ agg,
                                                    float4* __restrict__ z_out)
{
    int n = blockIdx.x * blockDim.x + threadIdx.x;
    if (n < N_NODES) {
        float a = agg[n]; float4 vv = z_cur[n];
        vv.x += a; vv.y += a; vv.z += a; vv.w += a;
        z_out[n] = vv;
    }
}

// ---------------- launch ----------------

extern "C" void kernel_launch(void* const* d_in, const int* in_sizes, int n_in,
                              void* d_out, int out_size, void* d_ws, size_t ws_size,
                              hipStream_t stream)
{
    const float* z     = (const float*)d_in[0];
    const float* r     = (const float*)d_in[1];
    const float* r_hat = (const float*)d_in[2];
    const float* W     = (const float*)d_in[3];
    const float* b     = (const float*)d_in[4];
    const int*   src   = (const int*)d_in[5];
    const int*   dst   = (const int*)d_in[6];
    float* out = (float*)d_out;

    char* ws = (char*)d_ws;
    size_t off = 0;
    auto alloc = [&](size_t bytes) {
        void* p = ws + off;
        off += (bytes + 15) & ~(size_t)15;
        return p;
    };
    int*            packedA = (int*)alloc((size_t)N_EDGES * 4);
    unsigned short* c0a     = (unsigned short*)alloc((size_t)N_EDGES * 2);
    unsigned short* c1a     = (unsigned short*)alloc((size_t)N_EDGES * 2);
    unsigned short* c2a     = (unsigned short*)alloc((size_t)N_EDGES * 2);
    int*            counts  = (int*)alloc((size_t)NSB * K_BUCKETS * 4);
    int*            baseRel = (int*)alloc((size_t)NSB * K_BUCKETS * 4);
    int*            tot     = (int*)alloc((size_t)K_BUCKETS * 4);
    int*            bstart  = (int*)alloc((size_t)(K_BUCKETS + 1) * 4);
    float*          Sa      = (float*)alloc((size_t)N_NODES * 4);
    float*          Sb      = (float*)alloc((size_t)N_NODES * 4);
    float*          ubuf    = (float*)alloc((size_t)N_NODES * 4);
    float*          vbuf    = (float*)alloc((size_t)N_NODES * 4);
    float*          partial = (float*)alloc((size_t)K_BUCKETS * P_SPLIT * BUCKET * 4);
    size_t required = off;

    dim3 nblk((N_NODES + 255) / 256);

    if (ws_size >= required) {
        prep_kernel<<<nblk, 256, 0, stream>>>(
            (const float4*)z, (float4*)(out + 4 * (size_t)N_NODES), W, ubuf, vbuf);
        hist_kernel<<<NSB, 256, 0, stream>>>(dst, counts);
        scan_cols<<<K_BUCKETS, 256, 0, stream>>>(counts, baseRel, tot);
        scan_tot<<<1, 64, 0, stream>>>(tot, bstart);
        scatter_kernel<<<NSB, 256, 0, stream>>>(src, dst, r, r_hat, W, b,
                                                counts, baseRel, bstart,
                                                packedA, c0a, c1a, c2a);
        // layer 0
        pagg_kernel<<<K_BUCKETS * P_SPLIT, 1024, 0, stream>>>(
            packedA, c0a, bstart, ubuf, vbuf, partial);
        fin_kernel<<<nblk, 256, 0, stream>>>(
            (const float4*)z, partial, Sa, Sa, W, 0, ubuf, vbuf, (float4*)out);
        // layer 1
        pagg_kernel<<<K_BUCKETS * P_SPLIT, 1024, 0, stream>>>(
            packedA, c1a, bstart, ubuf, vbuf, partial);
        fin_kernel<<<nblk, 256, 0, stream>>>(
            (const float4*)z, partial, Sa, Sb, W, 1, ubuf, vbuf, (float4*)out);
        // layer 2
        pagg_kernel<<<K_BUCKETS * P_SPLIT, 1024, 0, stream>>>(
            packedA, c2a, bstart, ubuf, vbuf, partial);
        fin_kernel<<<nblk, 256, 0, stream>>>(
            (const float4*)z, partial, Sb, Sb, W, 2, ubuf, vbuf, (float4*)out);
    } else {
        // fallback: round-2 path
        float* agg   = (float*)d_ws;
        float* z_cur = agg + N_NODES;
        dim3 eblk((N_EDGES + 255) / 256);
        init_kernel<<<nblk, 256, 0, stream>>>(
            (const float4*)z, (float4*)z_cur,
            (float4*)(out + 4 * (size_t)N_NODES), agg);
        for (int i = 0; i < 3; ++i) {
            edge_kernel<<<eblk, 256, 0, stream>>>(
                z_cur, r, r_hat, src, dst, W + 12 * i, b + i, agg);
            if (i < 2)
                node_update<<<nblk, 256, 0, stream>>>((float4*)z_cur, agg);
            else
                final_update<<<nblk, 256, 0, stream>>>(
                    (const float4*)z_cur, agg, (float4*)out);
        }
    }
}